// Round 9
// baseline (7180.842 us; speedup 1.0000x reference)
//
#include <hip/hip_runtime.h>

#define TSTEPS 784
#define BATCH  256
#define HDIM   512
#define NCLS   10
#define NGRP   16
#define WGPG   8

typedef __bf16 bf16x8 __attribute__((ext_vector_type(8)));
typedef float  f32x4  __attribute__((ext_vector_type(4)));
typedef unsigned uint4v __attribute__((ext_vector_type(4)));
typedef unsigned long long u64;
typedef unsigned short u16;

static __device__ __forceinline__ u16 f2bf(float f) {
  unsigned u = __builtin_bit_cast(unsigned, f);
  u += 0x7fffu + ((u >> 16) & 1u);
  return (u16)(u >> 16);
}
static __device__ __forceinline__ float bf2f(unsigned s) {
  unsigned u = s << 16;
  return __builtin_bit_cast(float, u);
}

// ---------------- xp[t][b] = inputs[b][perm[t]] ----------------
__global__ __launch_bounds__(256) void gather_xp(const float* __restrict__ in,
                                                 const int* __restrict__ perm,
                                                 float* __restrict__ xp) {
  int t = blockIdx.x;
  int b = threadIdx.x;
  int p = perm[t];
  p = (p < 0) ? 0 : (p >= TSTEPS ? TSTEPS - 1 : p);
  xp[t * BATCH + b] = in[b * TSTEPS + p];
}

// ---------------- X = (triu(W,1) - triu(W,1)^T) / 32 ----------------
__global__ __launch_bounds__(256) void build_X(const float* __restrict__ W,
                                               float* __restrict__ X) {
  int idx = blockIdx.x * 256 + threadIdx.x;
  int i = idx >> 9, j = idx & 511;
  float v = 0.f;
  if (j > i) v = W[i * HDIM + j];
  else if (i > j) v = -W[j * HDIM + i];
  X[idx] = v * 0.03125f;
}

// ---------------- P = coef*X + I ----------------
__global__ __launch_bounds__(256) void axpyI(float* __restrict__ P,
                                             const float* __restrict__ X, float coef) {
  int idx = blockIdx.x * 256 + threadIdx.x;
  int i = idx >> 9, j = idx & 511;
  P[idx] = coef * X[idx] + ((i == j) ? 1.f : 0.f);
}

// ---------------- C = alpha*A*B (+I), 512^3 fp32, 64x64 tile ----------------
// fp32 vector GEMM [R2-R8 proven]. The expm chain NEEDS fp32-class accuracy.
__global__ __launch_bounds__(256) void gemm512(float* __restrict__ C,
                                               const float* __restrict__ A,
                                               const float* __restrict__ B,
                                               float alpha, int addI) {
  __shared__ float As[16][68];
  __shared__ float Bs[16][68];
  const int tx = threadIdx.x, ty = threadIdx.y;
  const int tid = ty * 16 + tx;
  const int ib = blockIdx.y, jb = blockIdx.x;
  const int ra = tid >> 2, ca = (tid & 3) << 2;
  const int rb = tid >> 4, cb = (tid & 15) << 2;
  float acc[4][4] = {};
  for (int kt = 0; kt < HDIM / 16; ++kt) {
    f32x4 av = *(const f32x4*)(A + (ib * 64 + ra) * HDIM + kt * 16 + ca);
    f32x4 bv = *(const f32x4*)(B + (kt * 16 + rb) * HDIM + jb * 64 + cb);
    __syncthreads();
    As[ca + 0][ra] = av[0];
    As[ca + 1][ra] = av[1];
    As[ca + 2][ra] = av[2];
    As[ca + 3][ra] = av[3];
    *(f32x4*)&Bs[rb][cb] = bv;
    __syncthreads();
#pragma unroll
    for (int kk = 0; kk < 16; ++kk) {
      f32x4 a4 = *(const f32x4*)&As[kk][ty << 2];
      f32x4 b4 = *(const f32x4*)&Bs[kk][tx << 2];
#pragma unroll
      for (int u = 0; u < 4; ++u)
#pragma unroll
        for (int v = 0; v < 4; ++v) acc[u][v] = fmaf(a4[u], b4[v], acc[u][v]);
    }
  }
#pragma unroll
  for (int u = 0; u < 4; ++u)
#pragma unroll
    for (int v = 0; v < 4; ++v) {
      int r = ib * 64 + (ty << 2) + u, c = jb * 64 + (tx << 2) + v;
      float val = alpha * acc[u][v];
      if (addI && r == c) val += 1.f;
      C[r * HDIM + c] = val;
    }
}

// ---------------- persistent RNN scan [R18: 4-chain amortized sync] ---------
// Ledger: one-chain protocol variants all land 2250-2400us (~7000cy/step);
// PMC shows compute ~1100cy -> ~5900cy/step is pure sync latency (flag
// detect + 32KB coherent load + publish). R18 amortizes it: each WG serves
// FOUR independent batch-group chains (32 WGs x 4 = 128 (group,slice)
// pairs). Per iteration = 4 steps: ONE fused flag wait (32 flags), ONE
// vmcnt(0) over 4x32KB tagged loads, then 4x (LDS stage -> MFMA -> packed
// tagged store -> s_barrier -> flag-hint publish). R17-proven pieces: tags
// as truth (FETCH==R6 => zero retries), flag as drain-free hint, packed
// u32 h (bit0 of lo = (s>>1)&1 step tag), sc1 scope. LDS = proven 64KB:
// tiles staged A,B then C,D (per-chain s_barrier orders tile reuse).
__global__ __launch_bounds__(256, 1) void rnn_main(
    const float* __restrict__ xp, const float* __restrict__ Borth,
    const float* __restrict__ W_in, const float* __restrict__ b_mod,
    const float* __restrict__ W_lin, const float* __restrict__ b_lin,
    unsigned* __restrict__ h0, unsigned* __restrict__ h1,
    unsigned* __restrict__ flags, float* __restrict__ out) {
  __shared__ unsigned tile0[8192], tile1[8192];  // 32 KB x 2

  const int wg = blockIdx.x;   // 0..31
  const int cs = wg & 7;       // column slice 0..7
  const int qg = wg >> 3;      // quad-group 0..3
  const int gbA = (qg << 2) + 0, gbB = (qg << 2) + 1;
  const int gbC = (qg << 2) + 2, gbD = (qg << 2) + 3;
  const int tid = threadIdx.x;
  const int wave = tid >> 6;
  const int lane = tid & 63;
  const int quad = lane >> 4;
  const int l16 = lane & 15;
  const int colg = (cs << 6) + (wave << 4) + l16;           // Bf column
  const int hbase = (cs << 6) + (wave << 4) + (quad << 2);  // epilogue h-col base

  // Borth fragments (round-hi split, proven numerics) -- shared by all chains
  bf16x8 Bfh[16], Bfl[16];
#pragma unroll
  for (int ki = 0; ki < 16; ++ki) {
#pragma unroll
    for (int j = 0; j < 8; ++j) {
      int k = (ki << 5) + (quad << 3) + j;
      float v = Borth[k * HDIM + colg];
      u16 hb = f2bf(v);
      u16 lb = f2bf(v - bf2f(hb));
      Bfh[ki][j] = __builtin_bit_cast(__bf16, hb);
      Bfl[ki][j] = __builtin_bit_cast(__bf16, lb);
    }
  }
  const f32x4 win4 = *(const f32x4*)(W_in + hbase);
  const f32x4 bm4 = *(const f32x4*)(b_mod + hbase);

  const u64 b0A = (u64)(h0 + (gbA << 13)), b1A = (u64)(h1 + (gbA << 13));
  const u64 b0B = (u64)(h0 + (gbB << 13)), b1B = (u64)(h1 + (gbB << 13));
  const u64 b0C = (u64)(h0 + (gbC << 13)), b1C = (u64)(h1 + (gbC << 13));
  const u64 b0D = (u64)(h0 + (gbD << 13)), b1D = (u64)(h1 + (gbD << 13));
  const unsigned vo0 = (unsigned)((tid + 0 * 256) << 4);
  const unsigned vo1 = (unsigned)((tid + 1 * 256) << 4);
  const unsigned vo2 = (unsigned)((tid + 2 * 256) << 4);
  const unsigned vo3 = (unsigned)((tid + 3 * 256) << 4);
  const unsigned vo4 = (unsigned)((tid + 4 * 256) << 4);
  const unsigned vo5 = (unsigned)((tid + 5 * 256) << 4);
  const unsigned vo6 = (unsigned)((tid + 6 * 256) << 4);
  const unsigned vo7 = (unsigned)((tid + 7 * 256) << 4);
  const unsigned soff = (unsigned)(((l16 << 9) + hbase) << 2);
  const unsigned swz = (unsigned)((l16 & 7) << 2);
  unsigned* const flagA = flags + ((((gbA << 3) + cs)) << 5);
  unsigned* const flagB = flags + ((((gbB << 3) + cs)) << 5);
  unsigned* const flagC = flags + ((((gbC << 3) + cs)) << 5);
  unsigned* const flagD = flags + ((((gbD << 3) + cs)) << 5);
  unsigned* const pollp = flags + (((qg << 5) + (lane & 31)) << 5);

  uint4v qA0, qA1, qA2, qA3, qA4, qA5, qA6, qA7;
  uint4v qB0, qB1, qB2, qB3, qB4, qB5, qB6, qB7;
  uint4v qC0, qC1, qC2, qC3, qC4, qC5, qC6, qC7;
  uint4v qD0, qD1, qD2, qD3, qD4, qD5, qD6, qD7;

#define ISSUE8(P, B)                                                        \
  asm volatile("global_load_dwordx4 %[q0], %[v0], %[b] sc1\n\t"             \
               "global_load_dwordx4 %[q1], %[v1], %[b] sc1\n\t"             \
               "global_load_dwordx4 %[q2], %[v2], %[b] sc1\n\t"             \
               "global_load_dwordx4 %[q3], %[v3], %[b] sc1\n\t"             \
               "global_load_dwordx4 %[q4], %[v4], %[b] sc1\n\t"             \
               "global_load_dwordx4 %[q5], %[v5], %[b] sc1\n\t"             \
               "global_load_dwordx4 %[q6], %[v6], %[b] sc1\n\t"             \
               "global_load_dwordx4 %[q7], %[v7], %[b] sc1"                 \
               : [q0] "=&v"(q##P##0), [q1] "=&v"(q##P##1),                  \
                 [q2] "=&v"(q##P##2), [q3] "=&v"(q##P##3),                  \
                 [q4] "=&v"(q##P##4), [q5] "=&v"(q##P##5),                  \
                 [q6] "=&v"(q##P##6), [q7] "=&v"(q##P##7)                   \
               : [v0] "v"(vo0), [v1] "v"(vo1), [v2] "v"(vo2),               \
                 [v3] "v"(vo3), [v4] "v"(vo4), [v5] "v"(vo5),               \
                 [v6] "v"(vo6), [v7] "v"(vo7), [b] "s"(B));
#define CHKG1(P, g)                                                         \
  if (pend##P & (1u << g)) {                                                \
    unsigned orv = (q##P##g[0] ^ rmask) | (q##P##g[1] ^ rmask) |            \
                   (q##P##g[2] ^ rmask) | (q##P##g[3] ^ rmask);             \
    if (!(orv & 1u)) pend##P &= ~(1u << g);                                 \
  }
#define CHK8(P)                                                             \
  CHKG1(P, 0) CHKG1(P, 1) CHKG1(P, 2) CHKG1(P, 3)                           \
  CHKG1(P, 4) CHKG1(P, 5) CHKG1(P, 6) CHKG1(P, 7)
#define RLDG1(P, g, B)                                                      \
  if (pend##P & (1u << g))                                                  \
    asm volatile("global_load_dwordx4 %0, %1, %2 sc1"                       \
                 : "=&v"(q##P##g) : "v"(vo##g), "s"(B));
#define RLD8(P, B)                                                          \
  RLDG1(P, 0, B) RLDG1(P, 1, B) RLDG1(P, 2, B) RLDG1(P, 3, B)               \
  RLDG1(P, 4, B) RLDG1(P, 5, B) RLDG1(P, 6, B) RLDG1(P, 7, B)
#define STG1(g, q, TL)                                                      \
  {                                                                         \
    int G = tid + ((g) << 8);                                               \
    int r = G >> 7;                                                         \
    unsigned dc = (unsigned)(G & 127) << 2;                                 \
    unsigned phys = ((unsigned)r << 9) | (dc ^ ((unsigned)(r & 7) << 2));   \
    *(uint4v*)(TL + phys) = q;                                              \
  }
#define STG8(P, TL)                                                         \
  STG1(0, q##P##0, TL) STG1(1, q##P##1, TL) STG1(2, q##P##2, TL)            \
  STG1(3, q##P##3, TL) STG1(4, q##P##4, TL) STG1(5, q##P##5, TL)            \
  STG1(6, q##P##6, TL) STG1(7, q##P##7, TL)
// compute + epilogue + tagged store + barrier + flag-hint publish
#define COMPUTE(P, TL, XS, WB, FLG)                                         \
  {                                                                         \
    f32x4 hh = {0.f, 0.f, 0.f, 0.f};                                        \
    f32x4 lh = {0.f, 0.f, 0.f, 0.f};                                        \
    f32x4 hl = {0.f, 0.f, 0.f, 0.f};                                        \
    _Pragma("unroll") for (int ki = 0; ki < 16; ++ki) {                     \
      unsigned dc0 = (unsigned)((ki << 5) + (quad << 3));                   \
      unsigned base = (unsigned)l16 << 9;                                   \
      uint4v e0 = *(const uint4v*)(TL + base + (dc0 ^ swz));                \
      uint4v e1 = *(const uint4v*)(TL + base + ((dc0 + 4) ^ swz));          \
      uint4v ahv, alv;                                                      \
      ahv[0] = __builtin_amdgcn_perm(e0[1], e0[0], 0x07060302u);            \
      ahv[1] = __builtin_amdgcn_perm(e0[3], e0[2], 0x07060302u);            \
      ahv[2] = __builtin_amdgcn_perm(e1[1], e1[0], 0x07060302u);            \
      ahv[3] = __builtin_amdgcn_perm(e1[3], e1[2], 0x07060302u);            \
      alv[0] = __builtin_amdgcn_perm(e0[1], e0[0], 0x05040100u);            \
      alv[1] = __builtin_amdgcn_perm(e0[3], e0[2], 0x05040100u);            \
      alv[2] = __builtin_amdgcn_perm(e1[1], e1[0], 0x05040100u);            \
      alv[3] = __builtin_amdgcn_perm(e1[3], e1[2], 0x05040100u);            \
      bf16x8 ah = __builtin_bit_cast(bf16x8, ahv);                          \
      bf16x8 al = __builtin_bit_cast(bf16x8, alv);                          \
      hh = __builtin_amdgcn_mfma_f32_16x16x32_bf16(Bfh[ki], ah, hh, 0, 0, 0); \
      lh = __builtin_amdgcn_mfma_f32_16x16x32_bf16(Bfh[ki], al, lh, 0, 0, 0); \
      hl = __builtin_amdgcn_mfma_f32_16x16x32_bf16(Bfl[ki], ah, hl, 0, 0, 0); \
    }                                                                       \
    uint4v sv;                                                              \
    _Pragma("unroll") for (int r = 0; r < 4; ++r) {                         \
      float pre = hh[r] + lh[r] + hl[r] + (XS)*win4[r];                     \
      float mm = fmaxf(fabsf(pre) + bm4[r], 0.f);                           \
      float hv = (pre > 0.f) ? mm : ((pre < 0.f) ? -mm : 0.f);              \
      u16 hbv = f2bf(hv);                                                   \
      u16 lbv = f2bf(hv - bf2f(hbv));                                       \
      sv[r] = ((unsigned)hbv << 16) | (unsigned)((lbv & 0xFFFEu) | wtag);   \
    }                                                                       \
    asm volatile("global_store_dwordx4 %0, %1, %2 sc1" ::"v"(soff),         \
                 "v"(sv), "s"(WB));                                         \
    asm volatile("s_barrier" ::: "memory");                                 \
    if (tid == 0)                                                           \
      __hip_atomic_store(FLG, (unsigned)(t + 1), __ATOMIC_RELAXED,          \
                         __HIP_MEMORY_SCOPE_AGENT);                         \
  }

  for (int t = 0; t < TSTEPS; ++t) {
    const unsigned rmask = ((t >> 1) & 1) ? 0xFFFFFFFFu : 0u;
    const unsigned wtag = (unsigned)(((t + 1) >> 1) & 1);
    const u64 rbA = (t & 1) ? b1A : b0A, wbA = (t & 1) ? b0A : b1A;
    const u64 rbB = (t & 1) ? b1B : b0B, wbB = (t & 1) ? b0B : b1B;
    const u64 rbC = (t & 1) ? b1C : b0C, wbC = (t & 1) ? b0C : b1C;
    const u64 rbD = (t & 1) ? b1D : b0D, wbD = (t & 1) ? b0D : b1D;

    // ---- fused flag wait: all 32 producers of this quad-group ----
    if (t) {
      int fspin = 0;
      for (;;) {
        unsigned fl = __hip_atomic_load(pollp, __ATOMIC_RELAXED,
                                        __HIP_MEMORY_SCOPE_AGENT);
        if (__ballot(fl >= (unsigned)t) == ~0ull) break;
        __builtin_amdgcn_s_sleep(1);
        if (++fspin > (1 << 13)) break;
      }
      __builtin_amdgcn_sched_barrier(0);
    }
    const float xsA = xp[t * BATCH + (gbA << 4) + l16];
    const float xsB = xp[t * BATCH + (gbB << 4) + l16];
    const float xsC = xp[t * BATCH + (gbC << 4) + l16];
    const float xsD = xp[t * BATCH + (gbD << 4) + l16];

    // ---- one fused bulk load: 4 x 32KB tagged; one vmcnt(0) ----
    ISSUE8(A, rbA) ISSUE8(B, rbB) ISSUE8(C, rbC) ISSUE8(D, rbD)
    {
      unsigned pendA = 0xffu, pendB = 0xffu, pendC = 0xffu, pendD = 0xffu;
      int spin = 0;
      for (;;) {
        asm volatile("s_waitcnt vmcnt(0)" ::: "memory");
        __builtin_amdgcn_sched_barrier(0);  // rule #18
        CHK8(A) CHK8(B) CHK8(C) CHK8(D)
        if (!(pendA | pendB | pendC | pendD)) break;
        if (++spin > (1 << 11)) break;  // diagnosability valve
        __builtin_amdgcn_s_sleep(1);
        RLD8(A, rbA) RLD8(B, rbB) RLD8(C, rbC) RLD8(D, rbD)
      }
    }

    // ---- chains A,B: stage -> sync -> compute/publish ----
    STG8(A, tile0) STG8(B, tile1)
    __syncthreads();
    COMPUTE(A, tile0, xsA, wbA, flagA)
    COMPUTE(B, tile1, xsB, wbB, flagB)
    // B's s_barrier: all waves past A,B compute -> tiles reusable
    STG8(C, tile0) STG8(D, tile1)
    __syncthreads();
    COMPUTE(C, tile0, xsC, wbC, flagC)
    COMPUTE(D, tile1, xsD, wbD, flagD)
    // D's s_barrier gates next iteration's staging
  }

  // ---- head: all 4 groups' h_784 in b0 (tag 0); cs==0 WGs only ----
  if (cs == 0) {
    {
      int fspin = 0;
      for (;;) {
        unsigned fl = __hip_atomic_load(pollp, __ATOMIC_RELAXED,
                                        __HIP_MEMORY_SCOPE_AGENT);
        if (__ballot(fl >= (unsigned)TSTEPS) == ~0ull) break;
        __builtin_amdgcn_s_sleep(1);
        if (++fspin > (1 << 13)) break;
      }
      __builtin_amdgcn_sched_barrier(0);
    }
#define HEADC(P)                                                            \
  {                                                                         \
    const unsigned rmask = 0u;                                              \
    unsigned pendA = 0xffu;                                                 \
    int spin = 0;                                                           \
    ISSUE8(A, b0##P)                                                        \
    for (;;) {                                                              \
      asm volatile("s_waitcnt vmcnt(0)" ::: "memory");                      \
      __builtin_amdgcn_sched_barrier(0);                                    \
      CHK8(A)                                                               \
      if (!pendA) break;                                                    \
      if (++spin > (1 << 11)) break;                                        \
      __builtin_amdgcn_s_sleep(1);                                          \
      RLD8(A, b0##P)                                                        \
    }                                                                       \
    STG8(A, tile0)                                                          \
    __syncthreads();                                                        \
    int row = tid >> 4;                                                     \
    int cls = tid & 15;                                                     \
    if (cls < NCLS) {                                                       \
      float acc = b_lin[cls];                                               \
      const float* wl = W_lin + cls * HDIM;                                 \
      for (int k = 0; k < HDIM; ++k) {                                      \
        unsigned phys = ((unsigned)row << 9) |                              \
                        ((unsigned)k ^ (((unsigned)row & 7) << 2));         \
        unsigned x = tile0[phys];                                           \
        float hv = bf2f(x >> 16) + bf2f(x & 0xFFFFu);                       \
        acc = fmaf(hv, wl[k], acc);                                         \
      }                                                                     \
      out[((gb##P << 4) + row) * NCLS + cls] = acc;                         \
    }                                                                       \
    __syncthreads();                                                        \
  }
    HEADC(A) HEADC(B) HEADC(C) HEADC(D)
  }
}

extern "C" void kernel_launch(void* const* d_in, const int* in_sizes, int n_in,
                              void* d_out, int out_size, void* d_ws, size_t ws_size,
                              hipStream_t stream) {
  const float* inputs = (const float*)d_in[0];  // 256x784
  const int* perm = (const int*)d_in[1];        // 784
  const float* W_skew = (const float*)d_in[2];  // 512x512
  const float* W_in = (const float*)d_in[3];    // 512
  const float* b_mod = (const float*)d_in[4];   // 512
  const float* W_lin = (const float*)d_in[5];   // 10x512
  const float* b_lin = (const float*)d_in[6];   // 10
  float* out = (float*)d_out;

  char* ws = (char*)d_ws;
  unsigned* flags = (unsigned*)ws;            // 32 KB (128 slots x 128B)
  unsigned* h0 = (unsigned*)(ws + 32768);     // 512 KB (packed hi|lo u32)
  unsigned* h1 = h0 + BATCH * HDIM;           // 512 KB
  float* xp = (float*)(h1 + BATCH * HDIM);    // 0.77 MB
  float* X = xp + TSTEPS * BATCH;             // 1 MB
  float* P = X + HDIM * HDIM;                 // 1 MB
  float* Q = P + HDIM * HDIM;                 // 1 MB (total ~4.8 MB)

  // h0 = zeros (tag 0 == valid for t=0; h0 IS zero).
  // h1 = 0x01010101 (tag 1 == invalid until written).
  hipMemsetAsync(flags, 0, 32768, stream);
  hipMemsetAsync(h0, 0, (size_t)BATCH * HDIM * 4, stream);
  hipMemsetAsync(h1, 0x01, (size_t)BATCH * HDIM * 4, stream);

  gather_xp<<<TSTEPS, 256, 0, stream>>>(inputs, perm, xp);
  build_X<<<(HDIM * HDIM) / 256, 256, 0, stream>>>(W_skew, X);

  // expm(A) = (T6(A/32))^(2^5), Horner -- fp32 gemm512 [proven numerics]
  axpyI<<<(HDIM * HDIM) / 256, 256, 0, stream>>>(P, X, 1.f / 6.f);
  float* a = P;
  float* b = Q;
  for (int k = 5; k >= 1; --k) {
    gemm512<<<dim3(8, 8), dim3(16, 16), 0, stream>>>(b, X, a, 1.f / (float)k, 1);
    float* tmp = a; a = b; b = tmp;
  }
  for (int i = 0; i < 5; ++i) {
    gemm512<<<dim3(8, 8), dim3(16, 16), 0, stream>>>(b, a, a, 1.f, 0);
    float* tmp = a; a = b; b = tmp;
  }
  // a == P (10 swaps -> back to P)

  rnn_main<<<32, 256, 0, stream>>>(xp, a, W_in, b_mod, W_lin, b_lin,
                                   h0, h1, flags, out);
  (void)in_sizes; (void)n_in; (void)out_size; (void)ws_size;
}